// Round 2
// baseline (435.747 us; speedup 1.0000x reference)
//
#include <hip/hip_runtime.h>

// MaskedSelfAttention: B=4, S=4096, D=1024, H=128. fp32 in/out, bf16 MFMA compute.
// ws layout (12 MiB): Qb bf16[16384][128] | Kb bf16[16384][128] | Vt bf16[4][128][4096]

typedef __bf16 bf16x8 __attribute__((ext_vector_type(8)));
typedef __bf16 bf16x4 __attribute__((ext_vector_type(4)));
typedef float  f32x4  __attribute__((ext_vector_type(4)));

#define MFMA16(a, b, c) __builtin_amdgcn_mfma_f32_16x16x32_bf16(a, b, c, 0, 0, 0)

// -------------------------------------------------------------- qkv_gemm ----
// C = x[16384,1024] @ W^T, W in {Wq,Wk,Wv} selected by blockIdx.y. Block tile
// 128x128, 4 waves 2x2, wave tile 64x64 (4x4 MFMA 16x16x32). BK=64. W is
// converted fp32->bf16 during staging. Q/K stored row-major [s][h]; V stored
// transposed [b][h][s] (bf16x4 along s: C-layout regs are 4 consecutive rows).
__global__ __launch_bounds__(256) void qkv_gemm(
    const float* __restrict__ x,
    const float* __restrict__ Wq, const float* __restrict__ Wk,
    const float* __restrict__ Wv,
    const float* __restrict__ bq, const float* __restrict__ bk,
    const float* __restrict__ bv,
    __bf16* __restrict__ Qb, __bf16* __restrict__ Kb, __bf16* __restrict__ Vt)
{
    __shared__ __bf16 As[128][72];
    __shared__ __bf16 Bs[128][72];

    const int tid   = threadIdx.x;
    const int m0    = blockIdx.x * 128;
    const int which = blockIdx.y;           // 0=Q 1=K 2=V
    const float* W  = (which == 0) ? Wq : (which == 1) ? Wk : Wv;
    const int lane = tid & 63, wid = tid >> 6;
    const int quad = lane >> 4, l16 = lane & 15;
    const int wr = (wid >> 1) * 64, wc = (wid & 1) * 64;

    const f32x4 fzero = {0.f, 0.f, 0.f, 0.f};
    f32x4 acc[4][4];
#pragma unroll
    for (int i = 0; i < 4; ++i)
#pragma unroll
        for (int j = 0; j < 4; ++j) acc[i][j] = fzero;

    const int arow = tid >> 4, acol = (tid & 15) * 4;   // A: 8 passes x 16 rows
    const int brow = tid >> 3, bcol = (tid & 7) * 8;    // B: 4 passes x 32 rows

    for (int kk = 0; kk < 1024; kk += 64) {
#pragma unroll
        for (int p = 0; p < 8; ++p) {
            int r = p * 16 + arow;
            float4 v = *(const float4*)&x[(size_t)(m0 + r) * 1024 + kk + acol];
            bf16x4 pk = {(__bf16)v.x, (__bf16)v.y, (__bf16)v.z, (__bf16)v.w};
            *(bf16x4*)&As[r][acol] = pk;
        }
#pragma unroll
        for (int p = 0; p < 4; ++p) {
            int r = p * 32 + brow;                      // W row (head idx 0..127)
            float4 w0 = *(const float4*)&W[(size_t)r * 1024 + kk + bcol];
            float4 w1 = *(const float4*)&W[(size_t)r * 1024 + kk + bcol + 4];
            bf16x8 pk = {(__bf16)w0.x, (__bf16)w0.y, (__bf16)w0.z, (__bf16)w0.w,
                         (__bf16)w1.x, (__bf16)w1.y, (__bf16)w1.z, (__bf16)w1.w};
            *(bf16x8*)&Bs[r][bcol] = pk;
        }
        __syncthreads();
#pragma unroll
        for (int ks = 0; ks < 2; ++ks) {
            const int k0 = ks * 32 + quad * 8;
            bf16x8 a[4], bb[4];
#pragma unroll
            for (int mt = 0; mt < 4; ++mt)
                a[mt] = *(const bf16x8*)&As[wr + mt * 16 + l16][k0];
#pragma unroll
            for (int nt = 0; nt < 4; ++nt)
                bb[nt] = *(const bf16x8*)&Bs[wc + nt * 16 + l16][k0];
#pragma unroll
            for (int mt = 0; mt < 4; ++mt)
#pragma unroll
                for (int nt = 0; nt < 4; ++nt)
                    acc[mt][nt] = MFMA16(a[mt], bb[nt], acc[mt][nt]);
        }
        __syncthreads();
    }

    const float* bias = (which == 0) ? bq : (which == 1) ? bk : bv;
    if (which < 2) {
        __bf16* dst = (which == 0) ? Qb : Kb;
#pragma unroll
        for (int nt = 0; nt < 4; ++nt) {
            int col = wc + nt * 16 + l16;
            float bvv = bias[col];
#pragma unroll
            for (int mt = 0; mt < 4; ++mt)
#pragma unroll
                for (int r = 0; r < 4; ++r) {
                    int row = m0 + wr + mt * 16 + quad * 4 + r; // D: row=quad*4+reg
                    dst[(size_t)row * 128 + col] = (__bf16)(acc[mt][nt][r] + bvv);
                }
        }
    } else {
#pragma unroll
        for (int nt = 0; nt < 4; ++nt) {
            int col = wc + nt * 16 + l16;               // head index
            float bvv = bias[col];
#pragma unroll
            for (int mt = 0; mt < 4; ++mt) {
                int row = m0 + wr + mt * 16 + quad * 4; // global seq of reg 0
                int bb_ = row >> 12, s = row & 4095;    // batch, seq (tile within batch)
                bf16x4 pk = {(__bf16)(acc[mt][nt][0] + bvv),
                             (__bf16)(acc[mt][nt][1] + bvv),
                             (__bf16)(acc[mt][nt][2] + bvv),
                             (__bf16)(acc[mt][nt][3] + bvv)};
                *(bf16x4*)&Vt[((size_t)(bb_ * 128 + col)) * 4096 + s] = pk;
            }
        }
    }
}

// -------------------------------------------------------------- flash_attn --
// Grid (64,4): 64-row Q tiles. 4 waves/block, wave owns 16 q rows. Online
// softmax. K frags direct from global (row-major == K-major for QK^T), V frags
// direct from Vt. P: C-layout -> A-layout via LDS with __syncthreads (m120
// verified pattern; trip count is block-uniform so barrier is legal).
__global__ __launch_bounds__(256) void flash_attn(
    const __bf16* __restrict__ Qb, const __bf16* __restrict__ Kb,
    const __bf16* __restrict__ Vt, const int* __restrict__ mask,
    float* __restrict__ out)
{
    __shared__ __bf16 pl[4][16][72];
    const int b   = blockIdx.y;
    const int q0  = blockIdx.x * 64;
    const int tid = threadIdx.x, wid = tid >> 6, lane = tid & 63;
    const int quad = lane >> 4, l16 = lane & 15;
    const int rowbase = q0 + wid * 16 + quad * 4;      // D-layout row of reg 0
    const size_t sb = (size_t)b * 4096;
    const float scale = 0.08838834764831845f;          // 1/sqrt(128)

    bf16x8 qf[4];                                      // Q A-frags, whole head dim
#pragma unroll
    for (int h = 0; h < 4; ++h)
        qf[h] = *(const bf16x8*)&Qb[(sb + q0 + wid * 16 + l16) * 128 + h * 32 + quad * 8];

    float mi[4] = {-1e30f, -1e30f, -1e30f, -1e30f};
    float li[4] = {0.f, 0.f, 0.f, 0.f};
    const f32x4 fzero = {0.f, 0.f, 0.f, 0.f};
    f32x4 o[8];
#pragma unroll
    for (int hn = 0; hn < 8; ++hn) o[hn] = fzero;

    for (int k0 = 0; k0 <= q0; k0 += 64) {
        // ---- S = Q K^T (16x64 per wave) ----
        f32x4 s[4];
#pragma unroll
        for (int nt = 0; nt < 4; ++nt) s[nt] = fzero;
#pragma unroll
        for (int h = 0; h < 4; ++h) {
#pragma unroll
            for (int nt = 0; nt < 4; ++nt) {
                bf16x8 kf = *(const bf16x8*)
                    &Kb[(sb + k0 + nt * 16 + l16) * 128 + h * 32 + quad * 8];
                s[nt] = MFMA16(qf[h], kf, s[nt]);
            }
        }
        // ---- scale + causal/padding mask (sentinel -1e30 -> expf underflow 0)
        const bool diag = (k0 == q0);
#pragma unroll
        for (int nt = 0; nt < 4; ++nt) {
            int kc = k0 + nt * 16 + l16;
            bool mok = (mask[sb + kc] != 0);
#pragma unroll
            for (int r = 0; r < 4; ++r) {
                float v = s[nt][r] * scale;
                bool ok = mok && (!diag || kc <= rowbase + r);
                s[nt][r] = ok ? v : -1e30f;
            }
        }
        // ---- online softmax per owned row (16-lane groups share a row) ----
#pragma unroll
        for (int r = 0; r < 4; ++r) {
            float mx = fmaxf(fmaxf(s[0][r], s[1][r]), fmaxf(s[2][r], s[3][r]));
#pragma unroll
            for (int off = 1; off < 16; off <<= 1) mx = fmaxf(mx, __shfl_xor(mx, off));
            float mnew  = fmaxf(mi[r], mx);
            float alpha = __expf(mi[r] - mnew);        // mi=-1e30 -> 0, no NaN
            float rs = 0.f;
#pragma unroll
            for (int nt = 0; nt < 4; ++nt) {
                float p = __expf(s[nt][r] - mnew);     // masked -> exp(-huge)=0
                s[nt][r] = p;
                rs += p;
            }
#pragma unroll
            for (int off = 1; off < 16; off <<= 1) rs += __shfl_xor(rs, off);
            li[r] = li[r] * alpha + rs;
            mi[r] = mnew;
#pragma unroll
            for (int hn = 0; hn < 8; ++hn) o[hn][r] *= alpha;
        }
        // ---- P: C-layout -> A-layout via LDS round-trip ----
#pragma unroll
        for (int nt = 0; nt < 4; ++nt)
#pragma unroll
            for (int r = 0; r < 4; ++r)
                pl[wid][quad * 4 + r][nt * 16 + l16] = (__bf16)s[nt][r];
        __syncthreads();
        // ---- O += P V ----
#pragma unroll
        for (int ks = 0; ks < 2; ++ks) {
            bf16x8 ap = *(const bf16x8*)&pl[wid][l16][ks * 32 + quad * 8];
#pragma unroll
            for (int hn = 0; hn < 8; ++hn) {
                bf16x8 vf = *(const bf16x8*)
                    &Vt[(size_t)(b * 128 + hn * 16 + l16) * 4096 + k0 + ks * 32 + quad * 8];
                o[hn] = MFMA16(ap, vf, o[hn]);
            }
        }
        __syncthreads();
    }
    // ---- epilogue: normalize, fp32 store ----
#pragma unroll
    for (int r = 0; r < 4; ++r) {
        float inv = 1.0f / li[r];
#pragma unroll
        for (int hn = 0; hn < 8; ++hn)
            out[(sb + rowbase + r) * 128 + hn * 16 + l16] = o[hn][r] * inv;
    }
}

// ----------------------------------------------------------------- launch ---
extern "C" void kernel_launch(void* const* d_in, const int* in_sizes, int n_in,
                              void* d_out, int out_size, void* d_ws, size_t ws_size,
                              hipStream_t stream)
{
    const float* x    = (const float*)d_in[0];
    const int*   mask = (const int*)d_in[1];
    const float* Wq   = (const float*)d_in[2];
    const float* bq   = (const float*)d_in[3];
    const float* Wk   = (const float*)d_in[4];
    const float* bk   = (const float*)d_in[5];
    const float* Wv   = (const float*)d_in[6];
    const float* bv   = (const float*)d_in[7];
    float* out = (float*)d_out;

    char* ws = (char*)d_ws;
    __bf16* Qb = (__bf16*)ws;                     // 16384*128*2 = 4 MiB
    __bf16* Kb = Qb + (size_t)16384 * 128;        // 4 MiB
    __bf16* Vt = Kb + (size_t)16384 * 128;        // 4 MiB ([b][h][s])

    qkv_gemm<<<dim3(128, 3), 256, 0, stream>>>(x, Wq, Wk, Wv, bq, bk, bv, Qb, Kb, Vt);
    flash_attn<<<dim3(64, 4), 256, 0, stream>>>(Qb, Kb, Vt, mask, out);
}

// Round 3
// 378.795 us; speedup vs baseline: 1.1503x; 1.1503x over previous
//
#include <hip/hip_runtime.h>

// MaskedSelfAttention: B=4, S=4096, D=1024, H=128. fp32 in/out, bf16 MFMA compute.
// ws layout (12 MiB): Qb bf16[16384][128] | Kb bf16[16384][128] | Vt bf16[4][128][4096]

typedef __bf16 bf16x8 __attribute__((ext_vector_type(8)));
typedef __bf16 bf16x4 __attribute__((ext_vector_type(4)));
typedef float  f32x4  __attribute__((ext_vector_type(4)));

#define MFMA16(a, b, c) __builtin_amdgcn_mfma_f32_16x16x32_bf16(a, b, c, 0, 0, 0)

// -------------------------------------------------------------- qkv_gemm ----
// C = x[16384,1024] @ W^T, W in {Wq,Wk,Wv} selected by blockIdx.y. Block tile
// 128x128, 4 waves 2x2, wave tile 64x64 (4x4 MFMA 16x16x32). BK=64. W is
// converted fp32->bf16 during staging. Q/K stored row-major [s][h]; V stored
// transposed [b][h][s] (bf16x4 along s: C-layout regs are 4 consecutive rows).
__global__ __launch_bounds__(256) void qkv_gemm(
    const float* __restrict__ x,
    const float* __restrict__ Wq, const float* __restrict__ Wk,
    const float* __restrict__ Wv,
    const float* __restrict__ bq, const float* __restrict__ bk,
    const float* __restrict__ bv,
    __bf16* __restrict__ Qb, __bf16* __restrict__ Kb, __bf16* __restrict__ Vt)
{
    __shared__ __bf16 As[128][72];
    __shared__ __bf16 Bs[128][72];

    const int tid   = threadIdx.x;
    const int m0    = blockIdx.x * 128;
    const int which = blockIdx.y;           // 0=Q 1=K 2=V
    const float* W  = (which == 0) ? Wq : (which == 1) ? Wk : Wv;
    const int lane = tid & 63, wid = tid >> 6;
    const int quad = lane >> 4, l16 = lane & 15;
    const int wr = (wid >> 1) * 64, wc = (wid & 1) * 64;

    const f32x4 fzero = {0.f, 0.f, 0.f, 0.f};
    f32x4 acc[4][4];
#pragma unroll
    for (int i = 0; i < 4; ++i)
#pragma unroll
        for (int j = 0; j < 4; ++j) acc[i][j] = fzero;

    const int arow = tid >> 4, acol = (tid & 15) * 4;   // A: 8 passes x 16 rows
    const int brow = tid >> 3, bcol = (tid & 7) * 8;    // B: 4 passes x 32 rows

    for (int kk = 0; kk < 1024; kk += 64) {
#pragma unroll
        for (int p = 0; p < 8; ++p) {
            int r = p * 16 + arow;
            float4 v = *(const float4*)&x[(size_t)(m0 + r) * 1024 + kk + acol];
            bf16x4 pk = {(__bf16)v.x, (__bf16)v.y, (__bf16)v.z, (__bf16)v.w};
            *(bf16x4*)&As[r][acol] = pk;
        }
#pragma unroll
        for (int p = 0; p < 4; ++p) {
            int r = p * 32 + brow;                      // W row (head idx 0..127)
            float4 w0 = *(const float4*)&W[(size_t)r * 1024 + kk + bcol];
            float4 w1 = *(const float4*)&W[(size_t)r * 1024 + kk + bcol + 4];
            bf16x8 pk = {(__bf16)w0.x, (__bf16)w0.y, (__bf16)w0.z, (__bf16)w0.w,
                         (__bf16)w1.x, (__bf16)w1.y, (__bf16)w1.z, (__bf16)w1.w};
            *(bf16x8*)&Bs[r][bcol] = pk;
        }
        __syncthreads();
#pragma unroll
        for (int ks = 0; ks < 2; ++ks) {
            const int k0 = ks * 32 + quad * 8;
            bf16x8 a[4], bb[4];
#pragma unroll
            for (int mt = 0; mt < 4; ++mt)
                a[mt] = *(const bf16x8*)&As[wr + mt * 16 + l16][k0];
#pragma unroll
            for (int nt = 0; nt < 4; ++nt)
                bb[nt] = *(const bf16x8*)&Bs[wc + nt * 16 + l16][k0];
#pragma unroll
            for (int mt = 0; mt < 4; ++mt)
#pragma unroll
                for (int nt = 0; nt < 4; ++nt)
                    acc[mt][nt] = MFMA16(a[mt], bb[nt], acc[mt][nt]);
        }
        __syncthreads();
    }

    const float* bias = (which == 0) ? bq : (which == 1) ? bk : bv;
    if (which < 2) {
        __bf16* dst = (which == 0) ? Qb : Kb;
#pragma unroll
        for (int nt = 0; nt < 4; ++nt) {
            int col = wc + nt * 16 + l16;
            float bvv = bias[col];
#pragma unroll
            for (int mt = 0; mt < 4; ++mt)
#pragma unroll
                for (int r = 0; r < 4; ++r) {
                    int row = m0 + wr + mt * 16 + quad * 4 + r; // D: row=quad*4+reg
                    dst[(size_t)row * 128 + col] = (__bf16)(acc[mt][nt][r] + bvv);
                }
        }
    } else {
#pragma unroll
        for (int nt = 0; nt < 4; ++nt) {
            int col = wc + nt * 16 + l16;               // head index
            float bvv = bias[col];
#pragma unroll
            for (int mt = 0; mt < 4; ++mt) {
                int row = m0 + wr + mt * 16 + quad * 4; // global seq of reg 0
                int bb_ = row >> 12, s = row & 4095;    // batch, seq
                bf16x4 pk = {(__bf16)(acc[mt][nt][0] + bvv),
                             (__bf16)(acc[mt][nt][1] + bvv),
                             (__bf16)(acc[mt][nt][2] + bvv),
                             (__bf16)(acc[mt][nt][3] + bvv)};
                *(bf16x4*)&Vt[((size_t)(bb_ * 128 + col)) * 4096 + s] = pk;
            }
        }
    }
}

// -------------------------------------------------------------- flash_attn --
// Task = 16-row q-tile; block = 4 waves splitting the key range round-robin
// (intra-block split-K). Each wave keeps private (m,l,O); LDS merge at end.
// Grid (256,4) = 1024 blocks -> 4 waves/SIMD occupancy + LPT-ish balance
// (blockIdx.x ascending = descending work). LDS: P-transpose buf (9KB)
// unioned with the 33KB partial-merge buffer -> 33.3KB -> 4 blocks/CU.
__global__ __launch_bounds__(256, 4) void flash_attn(
    const __bf16* __restrict__ Qb, const __bf16* __restrict__ Kb,
    const __bf16* __restrict__ Vt, const int* __restrict__ mask,
    float* __restrict__ out)
{
    __shared__ __align__(16) char smem[4 * 16 * 128 * 4 + 2 * 4 * 16 * 4];
    __bf16 (*pl)[16][72] = (__bf16(*)[16][72])smem;                  // in-loop
    float (*po)[16][128] = (float(*)[16][128])smem;                  // post-loop
    float (*pm)[16] = (float(*)[16])(smem + 4 * 16 * 128 * 4);
    float (*pll)[16] = (float(*)[16])(smem + 4 * 16 * 128 * 4 + 4 * 16 * 4);

    const int b    = blockIdx.y;
    const int tile = 255 - blockIdx.x;                 // longest work first
    const int r0   = tile * 16;
    const int tid = threadIdx.x, wid = tid >> 6, lane = tid & 63;
    const int quad = lane >> 4, l16 = lane & 15;
    const int rowbase = r0 + quad * 4;                 // C-layout row of reg 0
    const size_t sb = (size_t)b * 4096;
    const float scale = 0.08838834764831845f;          // 1/sqrt(128)
    const int nk = (r0 + 79) >> 6;                     // # of 64-key tiles

    bf16x8 qf[4];                                      // Q A-frags (16 rows)
#pragma unroll
    for (int h = 0; h < 4; ++h)
        qf[h] = *(const bf16x8*)&Qb[(sb + r0 + l16) * 128 + h * 32 + quad * 8];

    float mi[4] = {-1e30f, -1e30f, -1e30f, -1e30f};
    float li[4] = {0.f, 0.f, 0.f, 0.f};
    const f32x4 fzero = {0.f, 0.f, 0.f, 0.f};
    f32x4 o[8];
#pragma unroll
    for (int hn = 0; hn < 8; ++hn) o[hn] = fzero;

    for (int t = wid; t < nk; t += 4) {
        const int k0 = t * 64;
        // ---- S = Q K^T (16x64) ----
        f32x4 s[4];
#pragma unroll
        for (int nt = 0; nt < 4; ++nt) s[nt] = fzero;
#pragma unroll
        for (int h = 0; h < 4; ++h) {
#pragma unroll
            for (int nt = 0; nt < 4; ++nt) {
                bf16x8 kf = *(const bf16x8*)
                    &Kb[(sb + k0 + nt * 16 + l16) * 128 + h * 32 + quad * 8];
                s[nt] = MFMA16(qf[h], kf, s[nt]);
            }
        }
        // ---- scale + causal/padding mask ----
#pragma unroll
        for (int nt = 0; nt < 4; ++nt) {
            int kc = k0 + nt * 16 + l16;
            bool mok = (mask[sb + kc] != 0);
#pragma unroll
            for (int r = 0; r < 4; ++r) {
                float v = s[nt][r] * scale;
                bool ok = mok && (kc <= rowbase + r);
                s[nt][r] = ok ? v : -1e30f;
            }
        }
        // ---- online softmax per owned row ----
#pragma unroll
        for (int r = 0; r < 4; ++r) {
            float mx = fmaxf(fmaxf(s[0][r], s[1][r]), fmaxf(s[2][r], s[3][r]));
#pragma unroll
            for (int off = 1; off < 16; off <<= 1) mx = fmaxf(mx, __shfl_xor(mx, off));
            float mnew  = fmaxf(mi[r], mx);
            float alpha = __expf(mi[r] - mnew);
            float rs = 0.f;
#pragma unroll
            for (int nt = 0; nt < 4; ++nt) {
                float p = (s[nt][r] < -5e29f) ? 0.f : __expf(s[nt][r] - mnew);
                s[nt][r] = p;
                rs += p;
            }
#pragma unroll
            for (int off = 1; off < 16; off <<= 1) rs += __shfl_xor(rs, off);
            li[r] = li[r] * alpha + rs;
            mi[r] = mnew;
#pragma unroll
            for (int hn = 0; hn < 8; ++hn) o[hn][r] *= alpha;
        }
        // ---- P: C-layout -> A-layout via per-wave LDS (in-order DS) ----
#pragma unroll
        for (int nt = 0; nt < 4; ++nt)
#pragma unroll
            for (int r = 0; r < 4; ++r)
                pl[wid][quad * 4 + r][nt * 16 + l16] = (__bf16)s[nt][r];
        asm volatile("s_waitcnt lgkmcnt(0)" ::: "memory");
        // ---- O += P V ----
#pragma unroll
        for (int ks = 0; ks < 2; ++ks) {
            bf16x8 ap = *(const bf16x8*)&pl[wid][l16][ks * 32 + quad * 8];
#pragma unroll
            for (int hn = 0; hn < 8; ++hn) {
                bf16x8 vf = *(const bf16x8*)
                    &Vt[(size_t)(b * 128 + hn * 16 + l16) * 4096 + k0 + ks * 32 + quad * 8];
                o[hn] = MFMA16(ap, vf, o[hn]);
            }
        }
    }

    // ---- write per-wave partials (pl region dead from here) ----
    __syncthreads();
#pragma unroll
    for (int r = 0; r < 4; ++r) {
        pm[wid][quad * 4 + r]  = mi[r];   // uniform across the 16 l16 lanes
        pll[wid][quad * 4 + r] = li[r];
#pragma unroll
        for (int hn = 0; hn < 8; ++hn)
            po[wid][quad * 4 + r][hn * 16 + l16] = o[hn][r];
    }
    __syncthreads();

    // ---- merge 4 partials, normalize, store fp32 ----
    const int row = tid >> 4, col = (tid & 15) * 8;
    float m0_ = fmaxf(fmaxf(pm[0][row], pm[1][row]), fmaxf(pm[2][row], pm[3][row]));
    float e[4], L = 0.f;
#pragma unroll
    for (int w = 0; w < 4; ++w) {
        e[w] = __expf(pm[w][row] - m0_);
        L += pll[w][row] * e[w];
    }
    float inv = 1.0f / L;
    float res[8];
#pragma unroll
    for (int j = 0; j < 8; ++j) {
        float acc = 0.f;
#pragma unroll
        for (int w = 0; w < 4; ++w) acc += po[w][row][col + j] * e[w];
        res[j] = acc * inv;
    }
    float* op = &out[(sb + r0 + row) * 128 + col];
    *(float4*)op       = *(float4*)&res[0];
    *(float4*)(op + 4) = *(float4*)&res[4];
}

// ----------------------------------------------------------------- launch ---
extern "C" void kernel_launch(void* const* d_in, const int* in_sizes, int n_in,
                              void* d_out, int out_size, void* d_ws, size_t ws_size,
                              hipStream_t stream)
{
    const float* x    = (const float*)d_in[0];
    const int*   mask = (const int*)d_in[1];
    const float* Wq   = (const float*)d_in[2];
    const float* bq   = (const float*)d_in[3];
    const float* Wk   = (const float*)d_in[4];
    const float* bk   = (const float*)d_in[5];
    const float* Wv   = (const float*)d_in[6];
    const float* bv   = (const float*)d_in[7];
    float* out = (float*)d_out;

    char* ws = (char*)d_ws;
    __bf16* Qb = (__bf16*)ws;                     // 4 MiB
    __bf16* Kb = Qb + (size_t)16384 * 128;        // 4 MiB
    __bf16* Vt = Kb + (size_t)16384 * 128;        // 4 MiB ([b][h][s])

    qkv_gemm<<<dim3(128, 3), 256, 0, stream>>>(x, Wq, Wk, Wv, bq, bk, bv, Qb, Kb, Vt);
    flash_attn<<<dim3(256, 4), 256, 0, stream>>>(Qb, Kb, Vt, mask, out);
}

// Round 4
// 286.497 us; speedup vs baseline: 1.5209x; 1.3222x over previous
//
#include <hip/hip_runtime.h>

// MaskedSelfAttention: B=4, S=4096, D=1024, H=128. fp32 in/out, bf16 MFMA compute.
// ws (13.4 MiB): Qb bf16[16384][128] | Kb | Vt bf16[4][128][4096] | Wb bf16[384][1024]

typedef __bf16 bf16x8 __attribute__((ext_vector_type(8)));
typedef __bf16 bf16x4 __attribute__((ext_vector_type(4)));
typedef float  f32x4  __attribute__((ext_vector_type(4)));

#define MFMA16(a, b, c) __builtin_amdgcn_mfma_f32_16x16x32_bf16(a, b, c, 0, 0, 0)

// ---------------------------------------------------------------- prep_w ----
__global__ __launch_bounds__(256) void prep_w(
    const float* __restrict__ Wq, const float* __restrict__ Wk,
    const float* __restrict__ Wv, __bf16* __restrict__ Wb)
{
    int i = (blockIdx.x * 256 + threadIdx.x) * 4;      // 0..393215, step 4
    int row = i >> 10;
    const float* W = (row < 128) ? Wq : (row < 256) ? Wk : Wv;
    float4 v = *(const float4*)&W[(size_t)(row & 127) * 1024 + (i & 1023)];
    bf16x4 pk = {(__bf16)v.x, (__bf16)v.y, (__bf16)v.z, (__bf16)v.w};
    *(bf16x4*)&Wb[i] = pk;
}

// -------------------------------------------------------------- qkv_gemm ----
// C = x[16384,1024] @ W^T. Block tile 128x128, 4 waves 2x2, wave 64x64
// (4x4 MFMA 16x16x32), BK=64. A: fp32 x converted during staging. B: bf16 Wb
// copied with uint4 (no convert). Q/K row-major [s][h]; V transposed [b][h][s].
__global__ __launch_bounds__(256) void qkv_gemm(
    const float* __restrict__ x, const __bf16* __restrict__ Wb,
    const float* __restrict__ bq, const float* __restrict__ bk,
    const float* __restrict__ bv,
    __bf16* __restrict__ Qb, __bf16* __restrict__ Kb, __bf16* __restrict__ Vt)
{
    __shared__ __bf16 As[128][72];
    __shared__ __bf16 Bs[128][72];

    const int tid   = threadIdx.x;
    const int m0    = blockIdx.x * 128;
    const int which = blockIdx.y;           // 0=Q 1=K 2=V
    const int n0    = which * 128;          // Wb row base
    const int lane = tid & 63, wid = tid >> 6;
    const int quad = lane >> 4, l16 = lane & 15;
    const int wr = (wid >> 1) * 64, wc = (wid & 1) * 64;

    const f32x4 fzero = {0.f, 0.f, 0.f, 0.f};
    f32x4 acc[4][4];
#pragma unroll
    for (int i = 0; i < 4; ++i)
#pragma unroll
        for (int j = 0; j < 4; ++j) acc[i][j] = fzero;

    const int arow = tid >> 4, acol = (tid & 15) * 4;   // A: 8 passes x 16 rows
    const int brow = tid >> 3, bcol = (tid & 7) * 8;    // B: 4 passes x 32 rows

    for (int kk = 0; kk < 1024; kk += 64) {
#pragma unroll
        for (int p = 0; p < 8; ++p) {
            int r = p * 16 + arow;
            float4 v = *(const float4*)&x[(size_t)(m0 + r) * 1024 + kk + acol];
            bf16x4 pk = {(__bf16)v.x, (__bf16)v.y, (__bf16)v.z, (__bf16)v.w};
            *(bf16x4*)&As[r][acol] = pk;
        }
#pragma unroll
        for (int p = 0; p < 4; ++p) {
            int r = p * 32 + brow;
            *(uint4*)&Bs[r][bcol] =
                *(const uint4*)&Wb[(size_t)(n0 + r) * 1024 + kk + bcol];
        }
        __syncthreads();
#pragma unroll
        for (int ks = 0; ks < 2; ++ks) {
            const int k0 = ks * 32 + quad * 8;
            bf16x8 a[4], bb[4];
#pragma unroll
            for (int mt = 0; mt < 4; ++mt)
                a[mt] = *(const bf16x8*)&As[wr + mt * 16 + l16][k0];
#pragma unroll
            for (int nt = 0; nt < 4; ++nt)
                bb[nt] = *(const bf16x8*)&Bs[wc + nt * 16 + l16][k0];
#pragma unroll
            for (int mt = 0; mt < 4; ++mt)
#pragma unroll
                for (int nt = 0; nt < 4; ++nt)
                    acc[mt][nt] = MFMA16(a[mt], bb[nt], acc[mt][nt]);
        }
        __syncthreads();
    }

    const float* bias = (which == 0) ? bq : (which == 1) ? bk : bv;
    if (which < 2) {
        __bf16* dst = (which == 0) ? Qb : Kb;
#pragma unroll
        for (int nt = 0; nt < 4; ++nt) {
            int col = wc + nt * 16 + l16;
            float bvv = bias[col];
#pragma unroll
            for (int mt = 0; mt < 4; ++mt)
#pragma unroll
                for (int r = 0; r < 4; ++r) {
                    int row = m0 + wr + mt * 16 + quad * 4 + r; // D: row=quad*4+reg
                    dst[(size_t)row * 128 + col] = (__bf16)(acc[mt][nt][r] + bvv);
                }
        }
    } else {
#pragma unroll
        for (int nt = 0; nt < 4; ++nt) {
            int col = wc + nt * 16 + l16;               // head index
            float bvv = bias[col];
#pragma unroll
            for (int mt = 0; mt < 4; ++mt) {
                int row = m0 + wr + mt * 16 + quad * 4; // global seq of reg 0
                int bb_ = row >> 12, s = row & 4095;
                bf16x4 pk = {(__bf16)(acc[mt][nt][0] + bvv),
                             (__bf16)(acc[mt][nt][1] + bvv),
                             (__bf16)(acc[mt][nt][2] + bvv),
                             (__bf16)(acc[mt][nt][3] + bvv)};
                *(bf16x4*)&Vt[((size_t)(bb_ * 128 + col)) * 4096 + s] = pk;
            }
        }
    }
}

// -------------------------------------------------------------- flash_attn --
// Task = 16-row q-tile; 4 waves split keys round-robin, private (m,l,O), LDS
// merge at end. v3: deep prefetch (K(t+4) + V(t) streams in flight behind
// softmax), launch_bounds(256,2) so VGPRs don't strangle MLP, whole-tile mask
// ballot with wave-uniform fast path, scale folded into Q frags.
__global__ __launch_bounds__(256, 2) void flash_attn(
    const __bf16* __restrict__ Qb, const __bf16* __restrict__ Kb,
    const __bf16* __restrict__ Vt, const int* __restrict__ mask,
    float* __restrict__ out)
{
    __shared__ __align__(16) char smem[4 * 16 * 128 * 4 + 2 * 4 * 16 * 4];
    __bf16 (*pl)[16][72] = (__bf16(*)[16][72])smem;                  // in-loop
    float (*po)[16][128] = (float(*)[16][128])smem;                  // post-loop
    float (*pm)[16] = (float(*)[16])(smem + 4 * 16 * 128 * 4);
    float (*pll)[16] = (float(*)[16])(smem + 4 * 16 * 128 * 4 + 4 * 16 * 4);

    const int b    = blockIdx.y;
    const int tile = 255 - blockIdx.x;                 // longest work first
    const int r0   = tile * 16;
    const int tid = threadIdx.x, wid = tid >> 6, lane = tid & 63;
    const int quad = lane >> 4, l16 = lane & 15;
    const int rowbase = r0 + quad * 4;                 // C-layout row of reg 0
    const size_t sb = (size_t)b * 4096;
    const float scale = 0.08838834764831845f;          // 1/sqrt(128)
    const int nk = (r0 + 79) >> 6;                     // # of 64-key tiles

    bf16x8 qf[4];                                      // Q A-frags, scale folded
#pragma unroll
    for (int h = 0; h < 4; ++h) {
        qf[h] = *(const bf16x8*)&Qb[(sb + r0 + l16) * 128 + h * 32 + quad * 8];
#pragma unroll
        for (int j = 0; j < 8; ++j) qf[h][j] = (__bf16)((float)qf[h][j] * scale);
    }

    float mi[4] = {-1e30f, -1e30f, -1e30f, -1e30f};
    float li[4] = {0.f, 0.f, 0.f, 0.f};
    const f32x4 fzero = {0.f, 0.f, 0.f, 0.f};
    f32x4 o[8];
#pragma unroll
    for (int hn = 0; hn < 8; ++hn) o[hn] = fzero;

    int t = wid;
    bf16x8 kf[4][4];                                   // K frags, current tile
    if (t < nk) {
        const int k0 = t * 64;
#pragma unroll
        for (int h = 0; h < 4; ++h)
#pragma unroll
            for (int nt = 0; nt < 4; ++nt)
                kf[h][nt] = *(const bf16x8*)
                    &Kb[(sb + k0 + nt * 16 + l16) * 128 + h * 32 + quad * 8];
    }

    for (; t < nk; t += 4) {
        const int k0 = t * 64;
        // ---- whole-tile mask ballot (1 coalesced load) ----
        int mv = mask[sb + k0 + lane];
        unsigned long long mb = __ballot(mv != 0);
        // ---- V(t) prefetch: in flight through QK + softmax ----
        bf16x8 vf[2][8];
#pragma unroll
        for (int ks = 0; ks < 2; ++ks)
#pragma unroll
            for (int hn = 0; hn < 8; ++hn)
                vf[ks][hn] = *(const bf16x8*)
                    &Vt[(size_t)(b * 128 + hn * 16 + l16) * 4096 + k0 + ks * 32 + quad * 8];
        // ---- S = Q K^T (16x64) ----
        f32x4 s[4];
#pragma unroll
        for (int nt = 0; nt < 4; ++nt) s[nt] = fzero;
#pragma unroll
        for (int h = 0; h < 4; ++h)
#pragma unroll
            for (int nt = 0; nt < 4; ++nt)
                s[nt] = MFMA16(qf[h], kf[h][nt], s[nt]);
        // ---- K(t+4) prefetch into freed kf regs ----
        if (t + 4 < nk) {
            const int kn = (t + 4) * 64;
#pragma unroll
            for (int h = 0; h < 4; ++h)
#pragma unroll
                for (int nt = 0; nt < 4; ++nt)
                    kf[h][nt] = *(const bf16x8*)
                        &Kb[(sb + kn + nt * 16 + l16) * 128 + h * 32 + quad * 8];
        }
        // ---- masking: fast path skips everything on interior unmasked tiles
        if (mb != ~0ull || k0 + 63 > r0) {
#pragma unroll
            for (int nt = 0; nt < 4; ++nt) {
                int kb_ = nt * 16 + l16;
                bool mok = (mb >> kb_) & 1;
                int kc = k0 + kb_;
#pragma unroll
                for (int r = 0; r < 4; ++r) {
                    bool ok = mok && (kc <= rowbase + r);
                    s[nt][r] = ok ? s[nt][r] : -1e30f;
                }
            }
        }
        // ---- online softmax per owned row ----
#pragma unroll
        for (int r = 0; r < 4; ++r) {
            float mx = fmaxf(fmaxf(s[0][r], s[1][r]), fmaxf(s[2][r], s[3][r]));
#pragma unroll
            for (int off = 1; off < 16; off <<= 1) mx = fmaxf(mx, __shfl_xor(mx, off));
            float mnew  = fmaxf(mi[r], mx);
            float alpha = __expf(mi[r] - mnew);
            float rs = 0.f;
#pragma unroll
            for (int nt = 0; nt < 4; ++nt) {
                float p = (s[nt][r] < -5e29f) ? 0.f : __expf(s[nt][r] - mnew);
                s[nt][r] = p;
                rs += p;
            }
#pragma unroll
            for (int off = 1; off < 16; off <<= 1) rs += __shfl_xor(rs, off);
            li[r] = li[r] * alpha + rs;
            mi[r] = mnew;
#pragma unroll
            for (int hn = 0; hn < 8; ++hn) o[hn][r] *= alpha;
        }
        // ---- P: C-layout -> A-layout via per-wave LDS (in-order DS) ----
#pragma unroll
        for (int nt = 0; nt < 4; ++nt)
#pragma unroll
            for (int r = 0; r < 4; ++r)
                pl[wid][quad * 4 + r][nt * 16 + l16] = (__bf16)s[nt][r];
        asm volatile("s_waitcnt lgkmcnt(0)" ::: "memory");
        // ---- O += P V (vf already in flight/landed) ----
#pragma unroll
        for (int ks = 0; ks < 2; ++ks) {
            bf16x8 ap = *(const bf16x8*)&pl[wid][l16][ks * 32 + quad * 8];
#pragma unroll
            for (int hn = 0; hn < 8; ++hn)
                o[hn] = MFMA16(ap, vf[ks][hn], o[hn]);
        }
    }

    // ---- write per-wave partials (pl region dead from here) ----
    __syncthreads();
#pragma unroll
    for (int r = 0; r < 4; ++r) {
        pm[wid][quad * 4 + r]  = mi[r];
        pll[wid][quad * 4 + r] = li[r];
#pragma unroll
        for (int hn = 0; hn < 8; ++hn)
            po[wid][quad * 4 + r][hn * 16 + l16] = o[hn][r];
    }
    __syncthreads();

    // ---- merge 4 partials, normalize, store fp32 ----
    const int row = tid >> 4, col = (tid & 15) * 8;
    float m0_ = fmaxf(fmaxf(pm[0][row], pm[1][row]), fmaxf(pm[2][row], pm[3][row]));
    float e[4], L = 0.f;
#pragma unroll
    for (int w = 0; w < 4; ++w) {
        e[w] = __expf(pm[w][row] - m0_);
        L += pll[w][row] * e[w];
    }
    float inv = 1.0f / L;
    float res[8];
#pragma unroll
    for (int j = 0; j < 8; ++j) {
        float acc = 0.f;
#pragma unroll
        for (int w = 0; w < 4; ++w) acc += po[w][row][col + j] * e[w];
        res[j] = acc * inv;
    }
    float* op = &out[(sb + r0 + row) * 128 + col];
    *(float4*)op       = *(float4*)&res[0];
    *(float4*)(op + 4) = *(float4*)&res[4];
}

// ----------------------------------------------------------------- launch ---
extern "C" void kernel_launch(void* const* d_in, const int* in_sizes, int n_in,
                              void* d_out, int out_size, void* d_ws, size_t ws_size,
                              hipStream_t stream)
{
    const float* x    = (const float*)d_in[0];
    const int*   mask = (const int*)d_in[1];
    const float* Wq   = (const float*)d_in[2];
    const float* bq   = (const float*)d_in[3];
    const float* Wk   = (const float*)d_in[4];
    const float* bk   = (const float*)d_in[5];
    const float* Wv   = (const float*)d_in[6];
    const float* bv   = (const float*)d_in[7];
    float* out = (float*)d_out;

    char* ws = (char*)d_ws;
    __bf16* Qb = (__bf16*)ws;                       // 4 MiB
    __bf16* Kb = Qb + (size_t)16384 * 128;          // 4 MiB
    __bf16* Vt = Kb + (size_t)16384 * 128;          // 4 MiB ([b][h][s])
    __bf16* Wb = Vt + (size_t)16384 * 128;          // 768 KiB

    prep_w<<<384, 256, 0, stream>>>(Wq, Wk, Wv, Wb);
    qkv_gemm<<<dim3(128, 3), 256, 0, stream>>>(x, Wb, bq, bk, bv, Qb, Kb, Vt);
    flash_attn<<<dim3(256, 4), 256, 0, stream>>>(Qb, Kb, Vt, mask, out);
}